// Round 1
// baseline (707.143 us; speedup 1.0000x reference)
//
#include <hip/hip_runtime.h>

#define N_NODES 200000
#define F_IN 128
#define HID 16

// ---------------- Stage 1: h = x @ W1  ([N,128] @ [128,16]) ----------------
__global__ __launch_bounds__(256) void gemm1_kernel(const float* __restrict__ x,
                                                    const float* __restrict__ W1,
                                                    float* __restrict__ h) {
    __shared__ float w[F_IN * HID];  // 8 KB
    int tid = threadIdx.x;
    for (int i = tid; i < F_IN * HID; i += 256) w[i] = W1[i];
    __syncthreads();

    int row = blockIdx.x * 256 + tid;
    if (row >= N_NODES) return;

    float acc[HID];
#pragma unroll
    for (int j = 0; j < HID; j++) acc[j] = 0.f;

    const float4* xr = reinterpret_cast<const float4*>(x + (size_t)row * F_IN);
#pragma unroll 4
    for (int k4 = 0; k4 < F_IN / 4; k4++) {
        float4 xv = xr[k4];
        const float* wr = &w[k4 * 4 * HID];
#pragma unroll
        for (int j = 0; j < HID; j++) acc[j] += xv.x * wr[j];
#pragma unroll
        for (int j = 0; j < HID; j++) acc[j] += xv.y * wr[HID + j];
#pragma unroll
        for (int j = 0; j < HID; j++) acc[j] += xv.z * wr[2 * HID + j];
#pragma unroll
        for (int j = 0; j < HID; j++) acc[j] += xv.w * wr[3 * HID + j];
    }

    float4* hr = reinterpret_cast<float4*>(h + (size_t)row * HID);
#pragma unroll
    for (int q = 0; q < HID / 4; q++)
        hr[q] = make_float4(acc[4 * q], acc[4 * q + 1], acc[4 * q + 2], acc[4 * q + 3]);
}

// ---------------- Stage 2/5: scatter-add  agg[dst] += h[src] * w -----------
__global__ __launch_bounds__(256) void scatter_kernel(const float* __restrict__ h,
                                                      const int* __restrict__ src,
                                                      const int* __restrict__ dst,
                                                      const float* __restrict__ ew,
                                                      float* __restrict__ agg,
                                                      int n_edges) {
    long long idx = (long long)blockIdx.x * 256 + threadIdx.x;
    long long total = (long long)n_edges * HID;
    if (idx >= total) return;
    int e = (int)(idx >> 4);
    int j = (int)(idx & (HID - 1));
    int s = src[e];
    int d = dst[e];
    float val = h[(size_t)s * HID + j] * ew[e];
    atomicAdd(&agg[(size_t)d * HID + j], val);
}

// ---------------- Stage 3: h2 = relu(agg + b1) @ W2 ------------------------
__global__ __launch_bounds__(256) void gemm2_kernel(const float* __restrict__ agg,
                                                    const float* __restrict__ b1,
                                                    const float* __restrict__ W2,
                                                    float* __restrict__ h2) {
    __shared__ float w[HID * HID];
    __shared__ float bias[HID];
    int tid = threadIdx.x;
    if (tid < HID * HID) w[tid] = W2[tid];
    if (tid < HID) bias[tid] = b1[tid];
    __syncthreads();

    int row = blockIdx.x * 256 + tid;
    if (row >= N_NODES) return;

    float hv[HID];
    const float4* ar = reinterpret_cast<const float4*>(agg + (size_t)row * HID);
#pragma unroll
    for (int q = 0; q < 4; q++) {
        float4 v = ar[q];
        hv[4 * q + 0] = fmaxf(v.x + bias[4 * q + 0], 0.f);
        hv[4 * q + 1] = fmaxf(v.y + bias[4 * q + 1], 0.f);
        hv[4 * q + 2] = fmaxf(v.z + bias[4 * q + 2], 0.f);
        hv[4 * q + 3] = fmaxf(v.w + bias[4 * q + 3], 0.f);
    }

    float acc[HID];
#pragma unroll
    for (int j = 0; j < HID; j++) acc[j] = 0.f;
#pragma unroll
    for (int k = 0; k < HID; k++) {
        float hk = hv[k];
#pragma unroll
        for (int j = 0; j < HID; j++) acc[j] += hk * w[k * HID + j];
    }

    float4* hr = reinterpret_cast<float4*>(h2 + (size_t)row * HID);
#pragma unroll
    for (int q = 0; q < 4; q++)
        hr[q] = make_float4(acc[4 * q], acc[4 * q + 1], acc[4 * q + 2], acc[4 * q + 3]);
}

// ---------------- Stage 6: out = relu(agg + b2) @ Wd + bd ------------------
__global__ __launch_bounds__(256) void final_kernel(const float* __restrict__ agg,
                                                    const float* __restrict__ b2,
                                                    const float* __restrict__ Wd,
                                                    const float* __restrict__ bd,
                                                    float* __restrict__ out) {
    __shared__ float wd[HID];
    __shared__ float bias[HID];
    __shared__ float bdv;
    int tid = threadIdx.x;
    if (tid < HID) { wd[tid] = Wd[tid]; bias[tid] = b2[tid]; }
    if (tid == 0) bdv = bd[0];
    __syncthreads();

    int row = blockIdx.x * 256 + tid;
    if (row >= N_NODES) return;

    const float4* ar = reinterpret_cast<const float4*>(agg + (size_t)row * HID);
    float acc = bdv;
#pragma unroll
    for (int q = 0; q < 4; q++) {
        float4 v = ar[q];
        acc += fmaxf(v.x + bias[4 * q + 0], 0.f) * wd[4 * q + 0];
        acc += fmaxf(v.y + bias[4 * q + 1], 0.f) * wd[4 * q + 1];
        acc += fmaxf(v.z + bias[4 * q + 2], 0.f) * wd[4 * q + 2];
        acc += fmaxf(v.w + bias[4 * q + 3], 0.f) * wd[4 * q + 3];
    }
    out[row] = acc;
}

extern "C" void kernel_launch(void* const* d_in, const int* in_sizes, int n_in,
                              void* d_out, int out_size, void* d_ws, size_t ws_size,
                              hipStream_t stream) {
    const float* x    = (const float*)d_in[0];
    const int*   esrc = (const int*)d_in[1];
    const int*   edst = (const int*)d_in[2];
    const float* ew   = (const float*)d_in[3];
    const float* W1   = (const float*)d_in[4];
    const float* b1   = (const float*)d_in[5];
    const float* W2   = (const float*)d_in[6];
    const float* b2   = (const float*)d_in[7];
    const float* Wd   = (const float*)d_in[8];
    const float* bd   = (const float*)d_in[9];
    float* out = (float*)d_out;

    int n_edges = in_sizes[1];

    float* bufA = (float*)d_ws;                         // [N,16] h_pre / h2_pre
    float* bufB = bufA + (size_t)N_NODES * HID;         // [N,16] agg
    size_t buf_bytes = (size_t)N_NODES * HID * sizeof(float);

    int node_blocks = (N_NODES + 255) / 256;
    long long scatter_work = (long long)n_edges * HID;
    int scatter_blocks = (int)((scatter_work + 255) / 256);

    // Layer 1
    gemm1_kernel<<<node_blocks, 256, 0, stream>>>(x, W1, bufA);
    hipMemsetAsync(bufB, 0, buf_bytes, stream);
    scatter_kernel<<<scatter_blocks, 256, 0, stream>>>(bufA, esrc, edst, ew, bufB, n_edges);

    // Layer 2 (transform fused with bias+relu of layer 1)
    gemm2_kernel<<<node_blocks, 256, 0, stream>>>(bufB, b1, W2, bufA);
    hipMemsetAsync(bufB, 0, buf_bytes, stream);
    scatter_kernel<<<scatter_blocks, 256, 0, stream>>>(bufA, esrc, edst, ew, bufB, n_edges);

    // Head
    final_kernel<<<node_blocks, 256, 0, stream>>>(bufB, b2, Wd, bd, out);
}